// Round 10
// baseline (33.767 us; speedup 1.0000x reference)
//
#include <hip/hip_runtime.h>

// Local 8x8 window autocorrelation, stride 4.
// x: (B, C, H, W) fp32 -> out: (B, C, nH, nW, KH, KW) fp32
// out[n, dy, dx] = sum_{i,j} p[i+dy-4][j+dx-4] * p[i][j]  (zero outside window)
//
// R10: each window is split across TWO waves (role per wave, no divergence):
//   block = 256 thr = 4 waves = 128 windows.
//   role A (waves 0,1): d=0 (dy4), d=1 (dy3) + c50            -> 748 FMA
//   role B (waves 2,3): d=2 (dy2), d=3 (dy1), d=4 (dy0) + c60,c70 -> 764 FMA
// This halves per-thread work and collapses live state (A: 2 rows + 17 acc;
// B: 5 rows + 26 acc) vs R9's ~120 (accA live through pass B -> 4 waves/SIMD).
// Sliding rows loaded JIT per step; latency hidden by 5-6 short waves/SIMD.
// Summation order per output cell identical to R8/R9 (r ascending).
// Staging/flush: proven byte-exact pattern - 64-window LDS slab (16.6KB),
// 2 phases; phase p staged by waves {p, p+2} (wave-uniform), flushed by all
// waves as 1KB contiguous full-sector stores (partial-sector writes cost
// 3-4.7x, R1/R4 evidence).

constexpr int KH = 8, KW = 8, SH = 4, SW = 4;
constexpr int B = 8, C = 64, H = 96, W = 96;
constexpr int nH = (H - KH) / SH + 1;  // 23
constexpr int nW = (W - KW) / SW + 1;  // 23
constexpr int NWIN = B * C * nH * nW;  // 270848 = 128 * 2116
constexpr int TPB = 256;
constexpr int WPB = 128;               // windows per block
constexpr int OSTRIDE = 65;            // 64 floats + 1 pad

__global__ __launch_bounds__(TPB) void
local_autocorr_kernel(const float* __restrict__ x, float* __restrict__ out) {
    __shared__ float lds[64 * OSTRIDE];  // 16640 B

    const int tid  = threadIdx.x;
    const int role = tid >> 7;           // 0: waves 0,1   1: waves 2,3
    const int k    = tid & 127;          // window within block
    const int n    = blockIdx.x * WPB + k;

    const int w  = n % nW;
    const int tt = n / nW;
    const int h  = tt % nH;
    const int bc = tt / nH;  // b*C + c

    const float* xp = x + ((size_t)bc * H + (size_t)h * SH) * W + (size_t)w * SW;

    float acc4[8], acc3[8], acc2[8], acc1[8], acc0[8];
    float c50 = 0.f, c60 = 0.f, c70 = 0.f;

    if (role == 0) {
        // ---- role A: d=0 (dy=4), d=1 (dy=3), c50. Rows r-1, r live. ----
#pragma unroll
        for (int dx = 0; dx < 8; ++dx) { acc4[dx] = 0.f; acc3[dx] = 0.f; }
        float rows[8][8];
#pragma unroll
        for (int r = 0; r < 8; ++r) {
            const float4 lo = *reinterpret_cast<const float4*>(xp + (size_t)r * W);
            const float4 hi = *reinterpret_cast<const float4*>(xp + (size_t)r * W + 4);
            rows[r][0]=lo.x; rows[r][1]=lo.y; rows[r][2]=lo.z; rows[r][3]=lo.w;
            rows[r][4]=hi.x; rows[r][5]=hi.y; rows[r][6]=hi.z; rows[r][7]=hi.w;

            // d = 0 -> dy = 4
#pragma unroll
            for (int dx = 0; dx < 8; ++dx) {
                const int OX = dx - 4;
#pragma unroll
                for (int j = 0; j < 8; ++j) {
                    if (j + OX < 0 || j + OX >= 8) continue;  // static DCE
                    acc4[dx] = fmaf(rows[r][j + OX], rows[r][j], acc4[dx]);
                }
            }
            // d = 1 -> dy = 3 (+ folded cell (5,0))
            if (r >= 1) {
#pragma unroll
                for (int dx = 0; dx < 8; ++dx) {
                    const int OX = dx - 4;
#pragma unroll
                    for (int j = 0; j < 8; ++j) {
                        if (j + OX < 0 || j + OX >= 8) continue;
                        acc3[dx] = fmaf(rows[r - 1][j + OX], rows[r][j], acc3[dx]);
                    }
                }
                c50 = fmaf(rows[r][0], rows[r - 1][4], c50);
                c50 = fmaf(rows[r][1], rows[r - 1][5], c50);
                c50 = fmaf(rows[r][2], rows[r - 1][6], c50);
                c50 = fmaf(rows[r][3], rows[r - 1][7], c50);
            }
            __builtin_amdgcn_sched_barrier(0);
        }
    } else {
        // ---- role B: d=2 (dy=2), d=3 (dy=1), d=4 (dy=0), c60, c70. ----
#pragma unroll
        for (int dx = 0; dx < 8; ++dx) { acc2[dx] = 0.f; acc1[dx] = 0.f; acc0[dx] = 0.f; }
        float rows[8][8];
#pragma unroll
        for (int r = 0; r < 8; ++r) {
            const float4 lo = *reinterpret_cast<const float4*>(xp + (size_t)r * W);
            const float4 hi = *reinterpret_cast<const float4*>(xp + (size_t)r * W + 4);
            rows[r][0]=lo.x; rows[r][1]=lo.y; rows[r][2]=lo.z; rows[r][3]=lo.w;
            rows[r][4]=hi.x; rows[r][5]=hi.y; rows[r][6]=hi.z; rows[r][7]=hi.w;

            // d = 2 -> dy = 2 (+ folded cell (6,0))
            if (r >= 2) {
#pragma unroll
                for (int dx = 0; dx < 8; ++dx) {
                    const int OX = dx - 4;
#pragma unroll
                    for (int j = 0; j < 8; ++j) {
                        if (j + OX < 0 || j + OX >= 8) continue;
                        acc2[dx] = fmaf(rows[r - 2][j + OX], rows[r][j], acc2[dx]);
                    }
                }
                c60 = fmaf(rows[r][0], rows[r - 2][4], c60);
                c60 = fmaf(rows[r][1], rows[r - 2][5], c60);
                c60 = fmaf(rows[r][2], rows[r - 2][6], c60);
                c60 = fmaf(rows[r][3], rows[r - 2][7], c60);
            }
            // d = 3 -> dy = 1 (+ folded cell (7,0))
            if (r >= 3) {
#pragma unroll
                for (int dx = 0; dx < 8; ++dx) {
                    const int OX = dx - 4;
#pragma unroll
                    for (int j = 0; j < 8; ++j) {
                        if (j + OX < 0 || j + OX >= 8) continue;
                        acc1[dx] = fmaf(rows[r - 3][j + OX], rows[r][j], acc1[dx]);
                    }
                }
                c70 = fmaf(rows[r][0], rows[r - 3][4], c70);
                c70 = fmaf(rows[r][1], rows[r - 3][5], c70);
                c70 = fmaf(rows[r][2], rows[r - 3][6], c70);
                c70 = fmaf(rows[r][3], rows[r - 3][7], c70);
            }
            // d = 4 -> dy = 0
            if (r >= 4) {
#pragma unroll
                for (int dx = 0; dx < 8; ++dx) {
                    const int OX = dx - 4;
#pragma unroll
                    for (int j = 0; j < 8; ++j) {
                        if (j + OX < 0 || j + OX >= 8) continue;
                        acc0[dx] = fmaf(rows[r - 4][j + OX], rows[r][j], acc0[dx]);
                    }
                }
            }
            __builtin_amdgcn_sched_barrier(0);
        }
    }

    // ---- Two-phase stage + flush. Phase p: windows [64p, 64p+64) staged by
    //      waves p (role A halves) and p+2 (role B halves) - wave-uniform. ----
    float* obase = out + (size_t)blockIdx.x * WPB * 64;
#pragma unroll
    for (int p = 0; p < 2; ++p) {
        if ((k >> 6) == p) {
            float* slot = &lds[(k & 63) * OSTRIDE];
            if (role == 0) {
                // rows dy=3,4 + mirror row 5 (out[5][dx] = acc3[8-dx], [5][0]=c50)
                *reinterpret_cast<float4*>(slot + 24) = make_float4(acc3[0], acc3[1], acc3[2], acc3[3]);
                *reinterpret_cast<float4*>(slot + 28) = make_float4(acc3[4], acc3[5], acc3[6], acc3[7]);
                *reinterpret_cast<float4*>(slot + 32) = make_float4(acc4[0], acc4[1], acc4[2], acc4[3]);
                *reinterpret_cast<float4*>(slot + 36) = make_float4(acc4[4], acc4[5], acc4[6], acc4[7]);
                *reinterpret_cast<float4*>(slot + 40) = make_float4(c50,     acc3[7], acc3[6], acc3[5]);
                *reinterpret_cast<float4*>(slot + 44) = make_float4(acc3[4], acc3[3], acc3[2], acc3[1]);
            } else {
                // rows dy=0,1,2 + mirror rows 6,7
                *reinterpret_cast<float4*>(slot + 0)  = make_float4(acc0[0], acc0[1], acc0[2], acc0[3]);
                *reinterpret_cast<float4*>(slot + 4)  = make_float4(acc0[4], acc0[5], acc0[6], acc0[7]);
                *reinterpret_cast<float4*>(slot + 8)  = make_float4(acc1[0], acc1[1], acc1[2], acc1[3]);
                *reinterpret_cast<float4*>(slot + 12) = make_float4(acc1[4], acc1[5], acc1[6], acc1[7]);
                *reinterpret_cast<float4*>(slot + 16) = make_float4(acc2[0], acc2[1], acc2[2], acc2[3]);
                *reinterpret_cast<float4*>(slot + 20) = make_float4(acc2[4], acc2[5], acc2[6], acc2[7]);
                *reinterpret_cast<float4*>(slot + 48) = make_float4(c60,     acc2[7], acc2[6], acc2[5]);
                *reinterpret_cast<float4*>(slot + 52) = make_float4(acc2[4], acc2[3], acc2[2], acc2[1]);
                *reinterpret_cast<float4*>(slot + 56) = make_float4(c70,     acc1[7], acc1[6], acc1[5]);
                *reinterpret_cast<float4*>(slot + 60) = make_float4(acc1[4], acc1[3], acc1[2], acc1[1]);
            }
        }
        __syncthreads();
        // Flush 64 windows x 16 float4 = 1024 slots, 4 per thread; each wave
        // store covers 1KB contiguous (4 complete 256B window regions).
#pragma unroll
        for (int kk = 0; kk < 4; ++kk) {
            const int flat4 = tid + kk * TPB;   // 0..1023
            const float4 v = *reinterpret_cast<const float4*>(
                &lds[(flat4 >> 4) * OSTRIDE + (flat4 & 15) * 4]);
            *reinterpret_cast<float4*>(obase + (size_t)p * 64 * 64 + flat4 * 4) = v;
        }
        __syncthreads();  // WAR: protect slab before phase 1 restages
    }
}

extern "C" void kernel_launch(void* const* d_in, const int* in_sizes, int n_in,
                              void* d_out, int out_size, void* d_ws, size_t ws_size,
                              hipStream_t stream) {
    const float* x = (const float*)d_in[0];
    float* out = (float*)d_out;

    const int blocks = NWIN / WPB;  // 2116, exact
    local_autocorr_kernel<<<blocks, TPB, 0, stream>>>(x, out);
}

// Round 11
// 29.857 us; speedup vs baseline: 1.1310x; 1.1310x over previous
//
#include <hip/hip_runtime.h>

// Local 8x8 window autocorrelation, stride 4.
// x: (B, C, H, W) fp32 -> out: (B, C, nH, nW, KH, KW) fp32
// out[n, dy, dx] = sum_{i,j} p[i+dy-4][j+dx-4] * p[i][j]  (zero outside window)
//
// R11 = R9 (best: 31.4us) + deeper prefetch + XCD swizzle. R10's wave-role
// split regressed (2x row loads + 4-wave lockstep) and is reverted.
//  - One thread per window, TPB=64, sliding rows, central symmetry (1512 FMA).
//  - Two-pass d-split (A: d=0..2, B: d=3..4) keeps VGPR <= 128 (4 waves/SIMD;
//    occupancy steps are 8/4/2 waves at VGPR 64/128/256 - R8's 180 gave 2).
//  - PREFETCH DISTANCE 2: each row load gets ~2 FMA blocks (~580 issue cyc)
//    of cover vs ~290 at distance 1 - targets the cold-line (L3/HBM ~600-900
//    cyc) latency that R9's waves couldn't hide at 4 waves/SIMD.
//  - Bijective XCD swizzle (4232 = 8*529): each XCD gets a contiguous 529-
//    block span -> 2.4MB input slice fits its 4MB L2.
//  - LDS: 32-window slab (8.3KB), two-phase flush, 1KB full-sector wave
//    stores (partial-sector writes cost 3-4.7x: R1/R4 evidence; R2/R6/R7/R9
//    byte-exact).

constexpr int KH = 8, KW = 8, SH = 4, SW = 4;
constexpr int B = 8, C = 64, H = 96, W = 96;
constexpr int nH = (H - KH) / SH + 1;  // 23
constexpr int nW = (W - KW) / SW + 1;  // 23
constexpr int NWIN = B * C * nH * nW;  // 270848 = 64 * 4232
constexpr int TPB = 64;
constexpr int HALFW = 32;              // windows staged per flush phase
constexpr int OSTRIDE = 65;            // 64 floats + 1 pad
constexpr int NBLK = NWIN / TPB;       // 4232 = 8 * 529
constexpr int NXCD = 8;
constexpr int CPX = NBLK / NXCD;       // 529

__global__ __launch_bounds__(TPB, 2) void
local_autocorr_kernel(const float* __restrict__ x, float* __restrict__ out) {
    __shared__ float lds[HALFW * OSTRIDE];  // 8320 B

    const int tid = threadIdx.x;
    // Bijective XCD swizzle: blocks bid%8==k form one contiguous span.
    const int bid = (int)blockIdx.x;
    const int blk = (bid % NXCD) * CPX + bid / NXCD;
    const int n = blk * TPB + tid;

    const int w  = n % nW;
    const int tt = n / nW;
    const int h  = tt % nH;
    const int bc = tt / nH;  // b*C + c

    const float* xp = x + ((size_t)bc * H + (size_t)h * SH) * W + (size_t)w * SW;

    float accA[3][8];   // accA[d] -> dy = 4-d, d = 0..2
    float c50 = 0.f, c60 = 0.f, c70 = 0.f;  // cells (5,0),(6,0),(7,0)
#pragma unroll
    for (int k = 0; k < 3; ++k)
#pragma unroll
        for (int dx = 0; dx < 8; ++dx) accA[k][dx] = 0.f;

#define LOADROW(dst, ri)                                                        \
    {                                                                           \
        const float4 lo_ = *reinterpret_cast<const float4*>(xp + (size_t)(ri)*W);     \
        const float4 hi_ = *reinterpret_cast<const float4*>(xp + (size_t)(ri)*W + 4); \
        dst[0]=lo_.x; dst[1]=lo_.y; dst[2]=lo_.z; dst[3]=lo_.w;                 \
        dst[4]=hi_.x; dst[5]=hi_.y; dst[6]=hi_.z; dst[7]=hi_.w;                 \
    }

    // ---- Pass A: d = 0..2 (rows r-2 .. r+2 live; prefetch distance 2) ----
    {
        float rows[8][8];
        LOADROW(rows[0], 0)
        LOADROW(rows[1], 1)
#pragma unroll
        for (int r = 0; r < 8; ++r) {
            if (r < 6) LOADROW(rows[r + 2], r + 2)
#pragma unroll
            for (int d = 0; d <= 2; ++d) {
                if (d > r) continue;  // static after unroll
#pragma unroll
                for (int dx = 0; dx < 8; ++dx) {
                    const int OX = dx - 4;
#pragma unroll
                    for (int j = 0; j < 8; ++j) {
                        if (j + OX < 0 || j + OX >= 8) continue;  // static DCE
                        accA[d][dx] = fmaf(rows[r-d][j+OX], rows[r][j], accA[d][dx]);
                    }
                }
                if (d == 1) {
                    c50 = fmaf(rows[r][0], rows[r-1][4], c50);
                    c50 = fmaf(rows[r][1], rows[r-1][5], c50);
                    c50 = fmaf(rows[r][2], rows[r-1][6], c50);
                    c50 = fmaf(rows[r][3], rows[r-1][7], c50);
                } else if (d == 2) {
                    c60 = fmaf(rows[r][0], rows[r-2][4], c60);
                    c60 = fmaf(rows[r][1], rows[r-2][5], c60);
                    c60 = fmaf(rows[r][2], rows[r-2][6], c60);
                    c60 = fmaf(rows[r][3], rows[r-2][7], c60);
                }
            }
            __builtin_amdgcn_sched_barrier(0);
        }
    }

    // Block cross-pass CSE: pass B must reload its rows (frees pass A's).
    asm volatile("" ::: "memory");

    float accB[2][8];   // accB[d-3] -> dy = 4-d, d = 3..4
#pragma unroll
    for (int k = 0; k < 2; ++k)
#pragma unroll
        for (int dx = 0; dx < 8; ++dx) accB[k][dx] = 0.f;

    // ---- Pass B: d = 3..4 (rows r-4 .. r+2 live; prefetch distance 2) ----
    {
        float rows[8][8];
#pragma unroll
        for (int k = 0; k < 5; ++k) LOADROW(rows[k], k)
#pragma unroll
        for (int r = 3; r < 8; ++r) {
            if (r < 6) LOADROW(rows[r + 2], r + 2)
#pragma unroll
            for (int d = 3; d <= 4; ++d) {
                if (d > r) continue;  // static after unroll
#pragma unroll
                for (int dx = 0; dx < 8; ++dx) {
                    const int OX = dx - 4;
#pragma unroll
                    for (int j = 0; j < 8; ++j) {
                        if (j + OX < 0 || j + OX >= 8) continue;  // static DCE
                        accB[d-3][dx] = fmaf(rows[r-d][j+OX], rows[r][j], accB[d-3][dx]);
                    }
                }
                if (d == 3) {
                    c70 = fmaf(rows[r][0], rows[r-3][4], c70);
                    c70 = fmaf(rows[r][1], rows[r-3][5], c70);
                    c70 = fmaf(rows[r][2], rows[r-3][6], c70);
                    c70 = fmaf(rows[r][3], rows[r-3][7], c70);
                }
            }
            __builtin_amdgcn_sched_barrier(0);
        }
    }
#undef LOADROW

    // ---- Two-phase stage + flush (8KB contiguous, full-sector stores) ----
    float* obase = out + (size_t)blk * TPB * 64;
#pragma unroll
    for (int ph = 0; ph < 2; ++ph) {
        if ((tid >> 5) == ph) {
            float* slot = &lds[(tid & 31) * OSTRIDE];
            // rows dy = 0..4 direct; 5..7 = mirror + folded cell.
            *reinterpret_cast<float4*>(slot + 0)  = make_float4(accB[1][0], accB[1][1], accB[1][2], accB[1][3]);
            *reinterpret_cast<float4*>(slot + 4)  = make_float4(accB[1][4], accB[1][5], accB[1][6], accB[1][7]);
            *reinterpret_cast<float4*>(slot + 8)  = make_float4(accB[0][0], accB[0][1], accB[0][2], accB[0][3]);
            *reinterpret_cast<float4*>(slot + 12) = make_float4(accB[0][4], accB[0][5], accB[0][6], accB[0][7]);
            *reinterpret_cast<float4*>(slot + 16) = make_float4(accA[2][0], accA[2][1], accA[2][2], accA[2][3]);
            *reinterpret_cast<float4*>(slot + 20) = make_float4(accA[2][4], accA[2][5], accA[2][6], accA[2][7]);
            *reinterpret_cast<float4*>(slot + 24) = make_float4(accA[1][0], accA[1][1], accA[1][2], accA[1][3]);
            *reinterpret_cast<float4*>(slot + 28) = make_float4(accA[1][4], accA[1][5], accA[1][6], accA[1][7]);
            *reinterpret_cast<float4*>(slot + 32) = make_float4(accA[0][0], accA[0][1], accA[0][2], accA[0][3]);
            *reinterpret_cast<float4*>(slot + 36) = make_float4(accA[0][4], accA[0][5], accA[0][6], accA[0][7]);
            *reinterpret_cast<float4*>(slot + 40) = make_float4(c50,        accA[1][7], accA[1][6], accA[1][5]);
            *reinterpret_cast<float4*>(slot + 44) = make_float4(accA[1][4], accA[1][3], accA[1][2], accA[1][1]);
            *reinterpret_cast<float4*>(slot + 48) = make_float4(c60,        accA[2][7], accA[2][6], accA[2][5]);
            *reinterpret_cast<float4*>(slot + 52) = make_float4(accA[2][4], accA[2][3], accA[2][2], accA[2][1]);
            *reinterpret_cast<float4*>(slot + 56) = make_float4(c70,        accB[0][7], accB[0][6], accB[0][5]);
            *reinterpret_cast<float4*>(slot + 60) = make_float4(accB[0][4], accB[0][3], accB[0][2], accB[0][1]);
        }
        __syncthreads();
        // Flush 32 windows x 16 float4 = 512 slots, 8 per thread; each wave
        // store covers 1KB contiguous (4 complete 256B window regions).
#pragma unroll
        for (int k = 0; k < 8; ++k) {
            const int flat4 = tid + k * 64;    // 0..511
            const float4 v = *reinterpret_cast<const float4*>(
                &lds[(flat4 >> 4) * OSTRIDE + (flat4 & 15) * 4]);
            *reinterpret_cast<float4*>(obase + (size_t)ph * HALFW * 64 + flat4 * 4) = v;
        }
        __syncthreads();  // WAR: protect LDS before next phase restages
    }
}

extern "C" void kernel_launch(void* const* d_in, const int* in_sizes, int n_in,
                              void* d_out, int out_size, void* d_ws, size_t ws_size,
                              hipStream_t stream) {
    const float* x = (const float*)d_in[0];
    float* out = (float*)d_out;

    local_autocorr_kernel<<<NBLK, TPB, 0, stream>>>(x, out);
}

// Round 12
// 29.562 us; speedup vs baseline: 1.1422x; 1.0100x over previous
//
#include <hip/hip_runtime.h>

// Local 8x8 window autocorrelation, stride 4.
// x: (B, C, H, W) fp32 -> out: (B, C, nH, nW, KH, KW) fp32
// out[n, dy, dx] = sum_{i,j} p[i+dy-4][j+dx-4] * p[i][j]  (zero outside window)
//
// R12: window split across TWO WAVES with disjoint d-sets (wave-uniform role,
// no divergence, no reduction):
//   wave 0 (role A): d=0 (dy4), d=1 (dy3) + c50             -> 748 FMA
//   wave 1 (role B): d=2 (dy2), d=3 (dy1), d=4 (dy0) + c60,c70 -> 764 FMA
// Purpose: R11 had 4232 waves = 4.1/SIMD available at 4/SIMD residency ->
// exactly ONE generation; the 67.7MB store flush (~11us of HBM drain) had no
// younger waves to hide behind. 8464 half-length waves -> ~2 generations:
// gen-2 compute overlaps gen-1 store drain. R10's version of this regressed
// from 4-wave lockstep + distance-0 loads + no swizzle; all fixed here.
//  - prefetch distance 2 (R11-proven), XCD swizzle (4232 = 8*529, bijective),
//  - single-phase LDS stage (64-window slab, 16.6KB) + 1KB full-sector wave
//    stores (partial-sector writes cost 3-4.7x: R1/R4; byte-exact since R6).
//  - __launch_bounds__(128,2): VGPR cap >=128 under both empirical (R3:
//    cap=256/w) and spec (512/w) readings - never caps below the live set.
// Summation order per output cell identical to R8..R11 (r ascending per d).

constexpr int KH = 8, KW = 8, SH = 4, SW = 4;
constexpr int B = 8, C = 64, H = 96, W = 96;
constexpr int nH = (H - KH) / SH + 1;  // 23
constexpr int nW = (W - KW) / SW + 1;  // 23
constexpr int NWIN = B * C * nH * nW;  // 270848 = 64 * 4232
constexpr int TPB = 128;
constexpr int WPB = 64;                // windows per block
constexpr int OSTRIDE = 65;            // 64 floats + 1 pad
constexpr int NBLK = NWIN / WPB;       // 4232 = 8 * 529
constexpr int NXCD = 8;
constexpr int CPX = NBLK / NXCD;       // 529

__global__ __launch_bounds__(TPB, 2) void
local_autocorr_kernel(const float* __restrict__ x, float* __restrict__ out) {
    __shared__ float lds[WPB * OSTRIDE];  // 16640 B

    const int tid  = threadIdx.x;
    const int role = tid >> 6;           // wave-uniform: wave 0 = A, wave 1 = B
    const int k    = tid & 63;           // window within block

    // Bijective XCD swizzle: blocks bid%8==c form one contiguous span.
    const int bid = (int)blockIdx.x;
    const int blk = (bid % NXCD) * CPX + bid / NXCD;
    const int n = blk * WPB + k;

    const int w  = n % nW;
    const int tt = n / nW;
    const int h  = tt % nH;
    const int bc = tt / nH;  // b*C + c

    const float* xp = x + ((size_t)bc * H + (size_t)h * SH) * W + (size_t)w * SW;

#define LOADROW(dst, ri)                                                              \
    {                                                                                 \
        const float4 lo_ = *reinterpret_cast<const float4*>(xp + (size_t)(ri)*W);     \
        const float4 hi_ = *reinterpret_cast<const float4*>(xp + (size_t)(ri)*W + 4); \
        dst[0]=lo_.x; dst[1]=lo_.y; dst[2]=lo_.z; dst[3]=lo_.w;                       \
        dst[4]=hi_.x; dst[5]=hi_.y; dst[6]=hi_.z; dst[7]=hi_.w;                       \
    }

    float* slot = &lds[k * OSTRIDE];

    if (role == 0) {
        // ---- role A: d=0 (dy=4), d=1 (dy=3), c50. Rows r-1..r+2 live. ----
        float accD0[8], accD1[8];
        float c50 = 0.f;
#pragma unroll
        for (int dx = 0; dx < 8; ++dx) { accD0[dx] = 0.f; accD1[dx] = 0.f; }

        float rows[8][8];
        LOADROW(rows[0], 0)
        LOADROW(rows[1], 1)
#pragma unroll
        for (int r = 0; r < 8; ++r) {
            if (r < 6) LOADROW(rows[r + 2], r + 2)
            // d = 0 -> dy = 4
#pragma unroll
            for (int dx = 0; dx < 8; ++dx) {
                const int OX = dx - 4;
#pragma unroll
                for (int j = 0; j < 8; ++j) {
                    if (j + OX < 0 || j + OX >= 8) continue;  // static DCE
                    accD0[dx] = fmaf(rows[r][j + OX], rows[r][j], accD0[dx]);
                }
            }
            // d = 1 -> dy = 3 (+ folded cell (5,0))
            if (r >= 1) {
#pragma unroll
                for (int dx = 0; dx < 8; ++dx) {
                    const int OX = dx - 4;
#pragma unroll
                    for (int j = 0; j < 8; ++j) {
                        if (j + OX < 0 || j + OX >= 8) continue;
                        accD1[dx] = fmaf(rows[r - 1][j + OX], rows[r][j], accD1[dx]);
                    }
                }
                c50 = fmaf(rows[r][0], rows[r - 1][4], c50);
                c50 = fmaf(rows[r][1], rows[r - 1][5], c50);
                c50 = fmaf(rows[r][2], rows[r - 1][6], c50);
                c50 = fmaf(rows[r][3], rows[r - 1][7], c50);
            }
            __builtin_amdgcn_sched_barrier(0);
        }

        // Stage rows dy=3,4 + mirror row 5 (out[5][dx] = accD1[8-dx], [5][0]=c50).
        *reinterpret_cast<float4*>(slot + 24) = make_float4(accD1[0], accD1[1], accD1[2], accD1[3]);
        *reinterpret_cast<float4*>(slot + 28) = make_float4(accD1[4], accD1[5], accD1[6], accD1[7]);
        *reinterpret_cast<float4*>(slot + 32) = make_float4(accD0[0], accD0[1], accD0[2], accD0[3]);
        *reinterpret_cast<float4*>(slot + 36) = make_float4(accD0[4], accD0[5], accD0[6], accD0[7]);
        *reinterpret_cast<float4*>(slot + 40) = make_float4(c50,      accD1[7], accD1[6], accD1[5]);
        *reinterpret_cast<float4*>(slot + 44) = make_float4(accD1[4], accD1[3], accD1[2], accD1[1]);
    } else {
        // ---- role B: d=2 (dy=2), d=3 (dy=1), d=4 (dy=0), c60, c70. ----
        float accD2[8], accD3[8], accD4[8];
        float c60 = 0.f, c70 = 0.f;
#pragma unroll
        for (int dx = 0; dx < 8; ++dx) { accD2[dx] = 0.f; accD3[dx] = 0.f; accD4[dx] = 0.f; }

        float rows[8][8];
#pragma unroll
        for (int kk = 0; kk < 4; ++kk) LOADROW(rows[kk], kk)
#pragma unroll
        for (int r = 2; r < 8; ++r) {
            if (r < 6) LOADROW(rows[r + 2], r + 2)
            // d = 2 -> dy = 2 (+ folded cell (6,0))
#pragma unroll
            for (int dx = 0; dx < 8; ++dx) {
                const int OX = dx - 4;
#pragma unroll
                for (int j = 0; j < 8; ++j) {
                    if (j + OX < 0 || j + OX >= 8) continue;
                    accD2[dx] = fmaf(rows[r - 2][j + OX], rows[r][j], accD2[dx]);
                }
            }
            c60 = fmaf(rows[r][0], rows[r - 2][4], c60);
            c60 = fmaf(rows[r][1], rows[r - 2][5], c60);
            c60 = fmaf(rows[r][2], rows[r - 2][6], c60);
            c60 = fmaf(rows[r][3], rows[r - 2][7], c60);
            // d = 3 -> dy = 1 (+ folded cell (7,0))
            if (r >= 3) {
#pragma unroll
                for (int dx = 0; dx < 8; ++dx) {
                    const int OX = dx - 4;
#pragma unroll
                    for (int j = 0; j < 8; ++j) {
                        if (j + OX < 0 || j + OX >= 8) continue;
                        accD3[dx] = fmaf(rows[r - 3][j + OX], rows[r][j], accD3[dx]);
                    }
                }
                c70 = fmaf(rows[r][0], rows[r - 3][4], c70);
                c70 = fmaf(rows[r][1], rows[r - 3][5], c70);
                c70 = fmaf(rows[r][2], rows[r - 3][6], c70);
                c70 = fmaf(rows[r][3], rows[r - 3][7], c70);
            }
            // d = 4 -> dy = 0
            if (r >= 4) {
#pragma unroll
                for (int dx = 0; dx < 8; ++dx) {
                    const int OX = dx - 4;
#pragma unroll
                    for (int j = 0; j < 8; ++j) {
                        if (j + OX < 0 || j + OX >= 8) continue;
                        accD4[dx] = fmaf(rows[r - 4][j + OX], rows[r][j], accD4[dx]);
                    }
                }
            }
            __builtin_amdgcn_sched_barrier(0);
        }

        // Stage rows dy=0,1,2 + mirror rows 6,7.
        *reinterpret_cast<float4*>(slot + 0)  = make_float4(accD4[0], accD4[1], accD4[2], accD4[3]);
        *reinterpret_cast<float4*>(slot + 4)  = make_float4(accD4[4], accD4[5], accD4[6], accD4[7]);
        *reinterpret_cast<float4*>(slot + 8)  = make_float4(accD3[0], accD3[1], accD3[2], accD3[3]);
        *reinterpret_cast<float4*>(slot + 12) = make_float4(accD3[4], accD3[5], accD3[6], accD3[7]);
        *reinterpret_cast<float4*>(slot + 16) = make_float4(accD2[0], accD2[1], accD2[2], accD2[3]);
        *reinterpret_cast<float4*>(slot + 20) = make_float4(accD2[4], accD2[5], accD2[6], accD2[7]);
        *reinterpret_cast<float4*>(slot + 48) = make_float4(c60,      accD2[7], accD2[6], accD2[5]);
        *reinterpret_cast<float4*>(slot + 52) = make_float4(accD2[4], accD2[3], accD2[2], accD2[1]);
        *reinterpret_cast<float4*>(slot + 56) = make_float4(c70,      accD3[7], accD3[6], accD3[5]);
        *reinterpret_cast<float4*>(slot + 60) = make_float4(accD3[4], accD3[3], accD3[2], accD3[1]);
    }
#undef LOADROW

    __syncthreads();

    // Flush: 64 windows x 16 float4 = 1024 slots, 8 per thread; each wave
    // store instruction covers 1KB contiguous (4 complete 256B regions).
    float* obase = out + (size_t)blk * WPB * 64;
#pragma unroll
    for (int kk = 0; kk < 8; ++kk) {
        const int flat4 = tid + kk * TPB;   // 0..1023
        const float4 v = *reinterpret_cast<const float4*>(
            &lds[(flat4 >> 4) * OSTRIDE + (flat4 & 15) * 4]);
        *reinterpret_cast<float4*>(obase + (size_t)flat4 * 4) = v;
    }
}

extern "C" void kernel_launch(void* const* d_in, const int* in_sizes, int n_in,
                              void* d_out, int out_size, void* d_ws, size_t ws_size,
                              hipStream_t stream) {
    const float* x = (const float*)d_in[0];
    float* out = (float*)d_out;

    local_autocorr_kernel<<<NBLK, TPB, 0, stream>>>(x, out);
}